// Round 28
// baseline (60.576 us; speedup 1.0000x reference)
//
#include <hip/hip_runtime.h>
#include <hip/hip_bf16.h>
#include <math.h>

#define NB 4
#define NN 512
#define DIN 128
#define DOUT 64
#define TI 2
#define CHROWS 64
#define NCHL 4          // 64-row chunks per block (j-half = 256 rows)
#define NTOT (NB * NN)  // 2048 rows

typedef __attribute__((ext_vector_type(8))) short short8;
typedef __attribute__((ext_vector_type(8))) unsigned short ushort8;
typedef __attribute__((ext_vector_type(16))) float f32x16;

typedef __attribute__((address_space(3))) unsigned int lds_u32;
typedef __attribute__((address_space(1))) unsigned int glb_u32;

#define C2F 2.885390081777927f   // 2*log2(e)

// Native RNE float->bf16 (v_cvt_pk_bf16_f32 on gfx950); bit-identical to the
// manual round-nearest-even emulation for finite values, ~2 fewer VALU ops.
__device__ __forceinline__ unsigned short f2bf(float f) {
    __hip_bfloat16 h = __float2bfloat16(f);
    return *(unsigned short*)&h;
}

__device__ __forceinline__ float bf2f(unsigned short u) {
    union { unsigned u; float f; } v; v.u = ((unsigned)u) << 16; return v.f;
}

// Blocks 0..255: convert x to bf16. Block 256: build apw fragment table with C2
// PRE-FOLDED: apwf[(oh*8+ks)*64+lane] = bf16(C2 * apw[oh*32+(lane&31)][ks*16+(lane>>5)*8..+8))
__global__ void x_to_bf16(const float* __restrict__ x, unsigned short* __restrict__ xbf,
                          const float* __restrict__ apw, unsigned short* __restrict__ apwf) {
    if (blockIdx.x == 256) {
        for (int i = threadIdx.x; i < 1024; i += 256) {
            const int oh = i >> 9, ks = (i >> 6) & 7, lane = i & 63;
            const int row = oh * 32 + (lane & 31);
            const int k0 = ks * 16 + (lane >> 5) * 8;
            const float* src = apw + row * DIN + k0;
            ushort8 fr;
            #pragma unroll
            for (int e = 0; e < 8; ++e) fr[e] = f2bf(C2F * src[e]);
            ((ushort8*)apwf)[i] = fr;
        }
        return;
    }
    const int idx = blockIdx.x * 256 + threadIdx.x;   // 0..65535
    float4 v = ((const float4*)x)[idx];
    ushort4 o;
    o.x = f2bf(v.x); o.y = f2bf(v.y); o.z = f2bf(v.z); o.w = f2bf(v.w);
    ((ushort4*)xbf)[idx] = o;
}

// Scores + exp + PARTIAL softmax (num/den) for one (row-pair, j-half).
// acc = C2*(S + bias) directly (C2 folded into A-frags, bias into MFMA C-init).
// Hazard-safe r27 body; ONLY change: launch_bounds (256,4) — the native-cvt
// A-prep lowered peak reg demand, so 4 waves/SIMD may now fit spill-free.
__global__ __launch_bounds__(256, 4) void gat_main(
    const float* __restrict__ x,            // [B][N][128] f32
    const unsigned short* __restrict__ xbf, // [B][N][128] bf16
    const unsigned short* __restrict__ apwf,// [2*8*64] short8 fragment table (C2-scaled)
    const float* __restrict__ apb,   // [64]
    const float* __restrict__ attw,  // [64]
    float* __restrict__ pnum,        // [2][NTOT][128]
    float* __restrict__ pden)        // [2][NTOT]
{
    __shared__ unsigned short xt[2][CHROWS * DIN];  // 2 x 16 KB dbuf tiles
    __shared__ float scp[2][TI][256];               // 4 KB [oh][i][jloc]
    __shared__ float xis[TI][DIN];                  // 1 KB query rows f32
    __shared__ float awm2_s[DOUT];                  // -2*attw (LDS-resident, POST reads)
    __shared__ float abc_s[DOUT];                   // apb*C2 (for accInit)
    __shared__ float red_s[4][TI];

    float* pagg = (float*)&xt[0][0];                // [8][TI][128] 8 KB alias

    const int t = threadIdx.x;
    const int blk = blockIdx.x;              // 0..2047
    const int jh = blk & 1;                  // j-half
    const int rp = blk >> 1;                 // row-pair 0..1023
    const int b = rp >> 8;
    const int rowbase = (rp & 255) * TI;
    const int rid0 = rp * TI;                // global row id base
    const float* xb = x + (size_t)b * NN * DIN;
    const unsigned short* xbb = xbf + (size_t)b * NN * DIN;
    const char* gsrcb = (const char*)xbb + (size_t)jh * 65536;   // this j-half

    const int lane = t & 63, wid = t >> 6;   // 4 waves
    const int qi = wid & 1;                  // query-row index this wave serves
    const int oh = wid >> 1;                 // o-half: o in [oh*32, oh*32+32)
    const int l31 = lane & 31;
    const int hi = lane >> 5;

// DMA staging: LDS linear (wave-uniform base + lane*16); swizzle applied on the
// GLOBAL source address (m173 pattern).
#define STAGE(BUF, CH) do {                                                     \
    _Pragma("unroll")                                                           \
    for (int k_ = 0; k_ < 4; ++k_) {                                            \
        const char* ga_ = gsrcb + (CH) * 16384 +                                \
            (k_ * 16 + (t >> 4)) * 256 + (((t & 15) ^ ((t >> 4) & 7)) << 4);    \
        lds_u32* lp_ = (lds_u32*)((char*)&xt[BUF][0] + k_ * 4096 + wid * 1024); \
        __builtin_amdgcn_global_load_lds((const glb_u32*)ga_, lp_, 16, 0, 0);   \
    }                                                                           \
} while (0)

    {
        const int i = t >> 7, d = t & 127;
        xis[i][d] = xb[(size_t)(rowbase + i) * DIN + d];
    }
    if (t < 64) { awm2_s[t] = -2.0f * attw[t]; abc_s[t] = C2F * apb[t]; }
    STAGE(0, 0);         // chunk-0 DMA in flight under A-prep
    __syncthreads();     // xis + awm2/abc + xt[0] visible

    // read offsets: row = s*32 + l31, logical granule = ks*2 + hi  (+s*8192)
    int rdoff[8];
    #pragma unroll
    for (int ks = 0; ks < 8; ++ks)
        rdoff[ks] = l31 * 256 + (((ks * 2 + hi) ^ (l31 & 7)) << 4);

    // A fragments from the coalesced table: afr[ks] = bf16(C2*w)*xi
    short8 afr[8];
    {
        const ushort8* awf = (const ushort8*)apwf + oh * 512;   // oh*8*64
        const float* xk0 = &xis[qi][0];
        #pragma unroll
        for (int ks = 0; ks < 8; ++ks) {
            ushort8 wv = awf[ks * 64 + lane];
            const float* xk = xk0 + ks * 16 + hi * 8;
            short8 fr;
            #pragma unroll
            for (int e = 0; e < 8; ++e)
                fr[e] = (short)f2bf(bf2f(wv[e]) * xk[e]);
            afr[ks] = fr;
        }
    }

    // per-lane base pointers into the LDS constant tables; crow(r)=(r&3)+8*(r>>2)+4*hi
    const float* aw2p = &awm2_s[oh * 32 + 4 * hi];
    const float* abcp = &abc_s[oh * 32 + 4 * hi];

    // accInit[r] = C2*bias for this lane's acc row r (MFMA C-input); also sumw.
    f32x16 accInit;
    float sumw = 0.0f;
    #pragma unroll
    for (int r = 0; r < 16; ++r) {
        const int off = (r & 3) + 8 * (r >> 2);
        accInit[r] = abcp[off];
        sumw += aw2p[off];
    }
    sumw *= -0.5f;   // sum of attw over this lane's 16 o's

#define COMPUTE(ACC, BUF, S) do {                                               \
    ACC = accInit;                                                              \
    _Pragma("unroll")                                                           \
    for (int ks_ = 0; ks_ < 8; ++ks_) {                                         \
        short8 bk_ = *(const short8*)((const char*)&xt[BUF][0] +                \
                                      rdoff[ks_] + (S) * 8192);                 \
        ACC = __builtin_amdgcn_mfma_f32_32x32x16_bf16(afr[ks_], bk_, ACC, 0, 0, 0); \
    }                                                                           \
} while (0)

// acc[r] is already C2*(S+bias): u = exp2(acc) = e^{2(S+b)}; w*tanh = w - 2w/(u+1)
#define POST(ACC, I32) do {                                                     \
    float sp_ = sumw;                                                           \
    _Pragma("unroll")                                                           \
    for (int r_ = 0; r_ < 16; ++r_) {                                           \
        float u_ = __builtin_amdgcn_exp2f(ACC[r_]);                             \
        float rc_ = __builtin_amdgcn_rcpf(u_ + 1.0f);                           \
        sp_ = fmaf(aw2p[(r_ & 3) + 8 * (r_ >> 2)], rc_, sp_);                   \
    }                                                                           \
    sp_ += __shfl_xor(sp_, 32);                                                 \
    if (lane < 32) scp[oh][qi][(I32) * 32 + l31] = sp_;                         \
} while (0)

    f32x16 a0, a1;

    // ch0 (buf0): next-chunk DMA issued first, in flight under COMPUTE+POST
    STAGE(1, 1);
    COMPUTE(a0, 0, 0);
    COMPUTE(a1, 0, 1);
    POST(a0, 0);
    POST(a1, 1);
    __syncthreads();
    // ch1 (buf1)
    STAGE(0, 2);
    COMPUTE(a0, 1, 0);
    COMPUTE(a1, 1, 1);
    POST(a0, 2);
    POST(a1, 3);
    __syncthreads();
    // ch2 (buf0)
    STAGE(1, 3);
    COMPUTE(a0, 0, 0);
    COMPUTE(a1, 0, 1);
    POST(a0, 4);
    POST(a1, 5);
    __syncthreads();
    // ch3 (buf1)
    COMPUTE(a0, 1, 0);
    COMPUTE(a1, 1, 1);
    POST(a0, 6);
    POST(a1, 7);
    __syncthreads();

    // exp + partial denominator (no max-subtraction: |score| <= sum|w| ~ 8)
    {
        float s0 = scp[0][0][t] + scp[1][0][t];
        float s1 = scp[0][1][t] + scp[1][1][t];
        float e0 = __expf(s0), e1 = __expf(s1);
        scp[0][0][t] = e0;   // esc[0][jloc]
        scp[0][1][t] = e1;   // esc[1][jloc]
        float ss0 = e0, ss1 = e1;
        #pragma unroll
        for (int m = 1; m < 64; m <<= 1) {
            ss0 += __shfl_xor(ss0, m);
            ss1 += __shfl_xor(ss1, m);
        }
        if (lane == 0) { red_s[wid][0] = ss0; red_s[wid][1] = ss1; }
    }
    __syncthreads();
    if (t < TI) {
        float den = red_s[0][t] + red_s[1][t] + red_s[2][t] + red_s[3][t];
        pden[jh * NTOT + rid0 + t] = den;
    }

    // partial numerator over this block's 256 j  — ushort4-vectorized
    const float* esc0 = &scp[0][0][0];
    const float* esc1 = &scp[0][1][0];
    {
        const int d0 = (t & 31) * 4, q = t >> 5;   // 8 groups of 32 j
        const unsigned short* xc = xbb + (size_t)(jh * 256) * DIN + d0;
        float b0[4] = {0.f, 0.f, 0.f, 0.f};
        float b1[4] = {0.f, 0.f, 0.f, 0.f};
        #pragma unroll 4
        for (int jj = q * 32; jj < q * 32 + 32; ++jj) {
            ushort4 xv = *(const ushort4*)(xc + (size_t)jj * DIN);
            float e0v = esc0[jj], e1v = esc1[jj];
            float x0 = bf2f(xv.x), x1 = bf2f(xv.y);
            float x2 = bf2f(xv.z), x3 = bf2f(xv.w);
            b0[0] = fmaf(e0v, x0, b0[0]); b0[1] = fmaf(e0v, x1, b0[1]);
            b0[2] = fmaf(e0v, x2, b0[2]); b0[3] = fmaf(e0v, x3, b0[3]);
            b1[0] = fmaf(e1v, x0, b1[0]); b1[1] = fmaf(e1v, x1, b1[1]);
            b1[2] = fmaf(e1v, x2, b1[2]); b1[3] = fmaf(e1v, x3, b1[3]);
        }
        #pragma unroll
        for (int c = 0; c < 4; ++c) {
            pagg[(q * TI + 0) * DIN + d0 + c] = b0[c];
            pagg[(q * TI + 1) * DIN + d0 + c] = b1[c];
        }
    }
    __syncthreads();
    {
        const int i = t >> 7, d = t & 127;
        float s = 0.f;
        #pragma unroll
        for (int q = 0; q < 8; ++q) s += pagg[(q * TI + i) * DIN + d];
        pnum[(size_t)(jh * NTOT + rid0 + i) * DIN + d] = s;
    }
#undef COMPUTE
#undef POST
#undef STAGE
}

// Combine j-half partials, normalize, apply both projections, emit BN partials.
// == r20 verified version: 128 blocks x 16 rows ==
__global__ __launch_bounds__(256, 2) void combine_proj(
    const float* __restrict__ x,
    const float* __restrict__ pnum, const float* __restrict__ pden,
    const float* __restrict__ pww, const float* __restrict__ pwb,
    const float* __restrict__ pow_, const float* __restrict__ pob,
    float* __restrict__ out, float* __restrict__ pbn)   // [128][2][64]
{
    __shared__ float wL[DOUT][DIN + 1];   // 33 KB (one matrix at a time)
    __shared__ float vL[16][DIN];         // 8 KB (num, then xi)
    __shared__ float invL[16];
    __shared__ float psum[4][DOUT];
    __shared__ float psum2[4][DOUT];

    const int t = threadIdx.x;
    const int rbase = blockIdx.x * 16;
    const int o = t & 63, rq = t >> 6;    // per-wave uniform rq

    // stage W1 + unnormalized num + inv-denominators (all coalesced)
    for (int k = t; k < DOUT * DIN; k += 256) wL[k >> 7][k & 127] = pww[k];
    for (int k = t; k < 16 * DIN; k += 256) {
        const int i = k >> 7, d = k & 127;
        const int r = rbase + i;
        vL[i][d] = pnum[(size_t)r * DIN + d] + pnum[(size_t)(NTOT + r) * DIN + d];
    }
    if (t < 16) {
        const int r = rbase + t;
        invL[t] = 1.0f / (pden[r] + pden[NTOT + r]);
    }
    __syncthreads();

    // phase 1: accp[rr] = W1[o,:] . num[row rq+rr*4]
    float accp[4] = {0.f, 0.f, 0.f, 0.f};
    #pragma unroll 4
    for (int d = 0; d < DIN; ++d) {
        float w = wL[o][d];
        #pragma unroll
        for (int rr = 0; rr < 4; ++rr)
            accp[rr] = fmaf(w, vL[rq + rr * 4][d], accp[rr]);
    }
    __syncthreads();

    // restage: W2 + xi rows
    for (int k = t; k < DOUT * DIN; k += 256) wL[k >> 7][k & 127] = pow_[k];
    for (int k = t; k < 16 * DIN; k += 256) {
        const int i = k >> 7, d = k & 127;
        vL[i][d] = x[(size_t)(rbase + i) * DIN + d];
    }
    __syncthreads();

    // phase 2: res[rr] = W2[o,:] . xi[row]; combine; write; BN partials
    float res[4] = {0.f, 0.f, 0.f, 0.f};
    #pragma unroll 4
    for (int d = 0; d < DIN; ++d) {
        float w = wL[o][d];
        #pragma unroll
        for (int rr = 0; rr < 4; ++rr)
            res[rr] = fmaf(w, vL[rq + rr * 4][d], res[rr]);
    }
    const float bias = pwb[o] + pob[o];
    float ls = 0.f, ls2 = 0.f;
    #pragma unroll
    for (int rr = 0; rr < 4; ++rr) {
        const int i = rq + rr * 4;
        float h = accp[rr] * invL[i] + res[rr] + bias;
        out[(size_t)(rbase + i) * DOUT + o] = h;
        ls += h; ls2 += h * h;
    }
    psum[rq][o] = ls;
    psum2[rq][o] = ls2;
    __syncthreads();
    if (t < DOUT) {
        pbn[((size_t)blockIdx.x * 2 + 0) * DOUT + t] =
            psum[0][t] + psum[1][t] + psum[2][t] + psum[3][t];
        pbn[((size_t)blockIdx.x * 2 + 1) * DOUT + t] =
            psum2[0][t] + psum2[1][t] + psum2[2][t] + psum2[3][t];
    }
}

// BN + SELU; every block first reduces the 128 per-block partials to stats
// (redundant but deterministic; avoids a separate finish launch).
__global__ __launch_bounds__(256) void bn_selu(
    float* __restrict__ out, const float* __restrict__ pbn,
    const float* __restrict__ gamma, const float* __restrict__ beta) {
    __shared__ float ps[4][DOUT], ps2[4][DOUT];
    __shared__ float stats[2][DOUT];
    const int t = threadIdx.x;
    {
        const int c = t & 63, grp = t >> 6;   // 4 groups of 32 partial-blocks
        float s = 0.f, s2 = 0.f;
        for (int bb = grp * 32; bb < grp * 32 + 32; ++bb) {
            s += pbn[((size_t)bb * 2 + 0) * DOUT + c];
            s2 += pbn[((size_t)bb * 2 + 1) * DOUT + c];
        }
        ps[grp][c] = s;
        ps2[grp][c] = s2;
    }
    __syncthreads();
    if (t < DOUT) {
        const float inv_n = 1.0f / (float)NTOT;
        float ss = ps[0][t] + ps[1][t] + ps[2][t] + ps[3][t];
        float ss2 = ps2[0][t] + ps2[1][t] + ps2[2][t] + ps2[3][t];
        float mean = ss * inv_n;
        float var = ss2 * inv_n - mean * mean;   // biased, as torch BN
        stats[0][t] = mean;
        stats[1][t] = rsqrtf(var + 1e-5f);
    }
    __syncthreads();
    const int idx = blockIdx.x * 256 + t;
    const int c = idx & 63;
    float v = out[idx];
    float y = (v - stats[0][c]) * stats[1][c] * gamma[c] + beta[c];
    const float scale = 1.0507009873554805f;
    const float alpha = 1.6732632423543772f;
    out[idx] = y > 0.0f ? scale * y : scale * alpha * (__expf(y) - 1.0f);
}

extern "C" void kernel_launch(void* const* d_in, const int* in_sizes, int n_in,
                              void* d_out, int out_size, void* d_ws, size_t ws_size,
                              hipStream_t stream) {
    const float* x    = (const float*)d_in[0];
    const float* apw  = (const float*)d_in[1];
    const float* apb  = (const float*)d_in[2];
    const float* attw = (const float*)d_in[3];
    const float* pww  = (const float*)d_in[4];
    const float* pwb  = (const float*)d_in[5];
    const float* pow_ = (const float*)d_in[6];
    const float* pob  = (const float*)d_in[7];
    const float* gmm  = (const float*)d_in[8];
    const float* bta  = (const float*)d_in[9];
    float* out = (float*)d_out;

    char* ws = (char*)d_ws;
    unsigned short* xbf = (unsigned short*)(ws + 1024);      // 512 KB
    float* pnum = (float*)(ws + 528384);                     // 2 MB  [2][2048][128]
    float* pden = (float*)(ws + 528384 + 2097152);           // 16 KB [2][2048]
    float* pbn  = (float*)(ws + 528384 + 2097152 + 16384);   // 64 KB [128][2][64]
    unsigned short* apwf = (unsigned short*)(ws + 528384 + 2097152 + 16384 + 65536); // 16 KB

    x_to_bf16<<<257, 256, 0, stream>>>(x, xbf, apw, apwf);
    gat_main<<<2 * NTOT / TI, 256, 0, stream>>>(x, xbf, apwf, apb, attw, pnum, pden);
    combine_proj<<<NTOT / 16, 256, 0, stream>>>(x, pnum, pden, pww, pwb, pow_, pob,
                                                out, pbn);
    bn_selu<<<(NTOT * DOUT) / 256, 256, 0, stream>>>(out, pbn, gmm, bta);
}

// Round 29
// 57.473 us; speedup vs baseline: 1.0540x; 1.0540x over previous
//
#include <hip/hip_runtime.h>
#include <hip/hip_bf16.h>
#include <math.h>

#define NB 4
#define NN 512
#define DIN 128
#define DOUT 64
#define TI 2
#define CHROWS 64
#define NCHL 4          // 64-row chunks per block (j-half = 256 rows)
#define NTOT (NB * NN)  // 2048 rows

typedef __attribute__((ext_vector_type(8))) short short8;
typedef __attribute__((ext_vector_type(8))) unsigned short ushort8;
typedef __attribute__((ext_vector_type(16))) float f32x16;

typedef __attribute__((address_space(3))) unsigned int lds_u32;
typedef __attribute__((address_space(1))) unsigned int glb_u32;

#define C2F 2.885390081777927f   // 2*log2(e)

// Native RNE float->bf16 (v_cvt_pk_bf16_f32 on gfx950); bit-identical to the
// manual round-nearest-even emulation for finite values, ~2 fewer VALU ops.
__device__ __forceinline__ unsigned short f2bf(float f) {
    __hip_bfloat16 h = __float2bfloat16(f);
    return *(unsigned short*)&h;
}

__device__ __forceinline__ float bf2f(unsigned short u) {
    union { unsigned u; float f; } v; v.u = ((unsigned)u) << 16; return v.f;
}

// Blocks 0..255: convert x to bf16. Block 256: build apw fragment table with C2
// PRE-FOLDED: apwf[(oh*8+ks)*64+lane] = bf16(C2 * apw[oh*32+(lane&31)][ks*16+(lane>>5)*8..+8))
__global__ void x_to_bf16(const float* __restrict__ x, unsigned short* __restrict__ xbf,
                          const float* __restrict__ apw, unsigned short* __restrict__ apwf) {
    if (blockIdx.x == 256) {
        for (int i = threadIdx.x; i < 1024; i += 256) {
            const int oh = i >> 9, ks = (i >> 6) & 7, lane = i & 63;
            const int row = oh * 32 + (lane & 31);
            const int k0 = ks * 16 + (lane >> 5) * 8;
            const float* src = apw + row * DIN + k0;
            ushort8 fr;
            #pragma unroll
            for (int e = 0; e < 8; ++e) fr[e] = f2bf(C2F * src[e]);
            ((ushort8*)apwf)[i] = fr;
        }
        return;
    }
    const int idx = blockIdx.x * 256 + threadIdx.x;   // 0..65535
    float4 v = ((const float4*)x)[idx];
    ushort4 o;
    o.x = f2bf(v.x); o.y = f2bf(v.y); o.z = f2bf(v.z); o.w = f2bf(v.w);
    ((ushort4*)xbf)[idx] = o;
}

// Scores + exp + PARTIAL softmax (num/den) for one (row-pair, j-half).
// acc = C2*(S + bias) directly (C2 folded into A-frags, bias into MFMA C-init).
// Hazard-safe body (intrinsic exp2/rcp); (256,3) reg cap -> spill-free.
__global__ __launch_bounds__(256, 3) void gat_main(
    const float* __restrict__ x,            // [B][N][128] f32
    const unsigned short* __restrict__ xbf, // [B][N][128] bf16
    const unsigned short* __restrict__ apwf,// [2*8*64] short8 fragment table (C2-scaled)
    const float* __restrict__ apb,   // [64]
    const float* __restrict__ attw,  // [64]
    float* __restrict__ pnum,        // [2][NTOT][128]
    float* __restrict__ pden)        // [2][NTOT]
{
    __shared__ unsigned short xt[2][CHROWS * DIN];  // 2 x 16 KB dbuf tiles
    __shared__ float scp[2][TI][256];               // 4 KB [oh][i][jloc]
    __shared__ float xis[TI][DIN];                  // 1 KB query rows f32
    __shared__ float awm2_s[DOUT];                  // -2*attw (LDS-resident, POST reads)
    __shared__ float abc_s[DOUT];                   // apb*C2 (for accInit)
    __shared__ float red_s[4][TI];

    float* pagg = (float*)&xt[0][0];                // [8][TI][128] 8 KB alias

    const int t = threadIdx.x;
    const int blk = blockIdx.x;              // 0..2047
    const int jh = blk & 1;                  // j-half
    const int rp = blk >> 1;                 // row-pair 0..1023
    const int b = rp >> 8;
    const int rowbase = (rp & 255) * TI;
    const int rid0 = rp * TI;                // global row id base
    const float* xb = x + (size_t)b * NN * DIN;
    const unsigned short* xbb = xbf + (size_t)b * NN * DIN;
    const char* gsrcb = (const char*)xbb + (size_t)jh * 65536;   // this j-half

    const int lane = t & 63, wid = t >> 6;   // 4 waves
    const int qi = wid & 1;                  // query-row index this wave serves
    const int oh = wid >> 1;                 // o-half: o in [oh*32, oh*32+32)
    const int l31 = lane & 31;
    const int hi = lane >> 5;

// DMA staging: LDS linear (wave-uniform base + lane*16); swizzle applied on the
// GLOBAL source address (m173 pattern).
#define STAGE(BUF, CH) do {                                                     \
    _Pragma("unroll")                                                           \
    for (int k_ = 0; k_ < 4; ++k_) {                                            \
        const char* ga_ = gsrcb + (CH) * 16384 +                                \
            (k_ * 16 + (t >> 4)) * 256 + (((t & 15) ^ ((t >> 4) & 7)) << 4);    \
        lds_u32* lp_ = (lds_u32*)((char*)&xt[BUF][0] + k_ * 4096 + wid * 1024); \
        __builtin_amdgcn_global_load_lds((const glb_u32*)ga_, lp_, 16, 0, 0);   \
    }                                                                           \
} while (0)

    {
        const int i = t >> 7, d = t & 127;
        xis[i][d] = xb[(size_t)(rowbase + i) * DIN + d];
    }
    if (t < 64) { awm2_s[t] = -2.0f * attw[t]; abc_s[t] = C2F * apb[t]; }
    STAGE(0, 0);         // chunk-0 DMA in flight under A-prep
    __syncthreads();     // xis + awm2/abc + xt[0] visible

    // read offsets: row = s*32 + l31, logical granule = ks*2 + hi  (+s*8192)
    int rdoff[8];
    #pragma unroll
    for (int ks = 0; ks < 8; ++ks)
        rdoff[ks] = l31 * 256 + (((ks * 2 + hi) ^ (l31 & 7)) << 4);

    // A fragments from the coalesced table: afr[ks] = bf16(C2*w)*xi
    short8 afr[8];
    {
        const ushort8* awf = (const ushort8*)apwf + oh * 512;   // oh*8*64
        const float* xk0 = &xis[qi][0];
        #pragma unroll
        for (int ks = 0; ks < 8; ++ks) {
            ushort8 wv = awf[ks * 64 + lane];
            const float* xk = xk0 + ks * 16 + hi * 8;
            short8 fr;
            #pragma unroll
            for (int e = 0; e < 8; ++e)
                fr[e] = (short)f2bf(bf2f(wv[e]) * xk[e]);
            afr[ks] = fr;
        }
    }

    // per-lane base pointers into the LDS constant tables; crow(r)=(r&3)+8*(r>>2)+4*hi
    const float* aw2p = &awm2_s[oh * 32 + 4 * hi];
    const float* abcp = &abc_s[oh * 32 + 4 * hi];

    // accInit[r] = C2*bias for this lane's acc row r (MFMA C-input); also sumw.
    f32x16 accInit;
    float sumw = 0.0f;
    #pragma unroll
    for (int r = 0; r < 16; ++r) {
        const int off = (r & 3) + 8 * (r >> 2);
        accInit[r] = abcp[off];
        sumw += aw2p[off];
    }
    sumw *= -0.5f;   // sum of attw over this lane's 16 o's

#define COMPUTE(ACC, BUF, S) do {                                               \
    ACC = accInit;                                                              \
    _Pragma("unroll")                                                           \
    for (int ks_ = 0; ks_ < 8; ++ks_) {                                         \
        short8 bk_ = *(const short8*)((const char*)&xt[BUF][0] +                \
                                      rdoff[ks_] + (S) * 8192);                 \
        ACC = __builtin_amdgcn_mfma_f32_32x32x16_bf16(afr[ks_], bk_, ACC, 0, 0, 0); \
    }                                                                           \
} while (0)

// acc[r] is already C2*(S+bias): u = exp2(acc) = e^{2(S+b)}; w*tanh = w - 2w/(u+1)
#define POST(ACC, I32) do {                                                     \
    float sp_ = sumw;                                                           \
    _Pragma("unroll")                                                           \
    for (int r_ = 0; r_ < 16; ++r_) {                                           \
        float u_ = __builtin_amdgcn_exp2f(ACC[r_]);                             \
        float rc_ = __builtin_amdgcn_rcpf(u_ + 1.0f);                           \
        sp_ = fmaf(aw2p[(r_ & 3) + 8 * (r_ >> 2)], rc_, sp_);                   \
    }                                                                           \
    sp_ += __shfl_xor(sp_, 32);                                                 \
    if (lane < 32) scp[oh][qi][(I32) * 32 + l31] = sp_;                         \
} while (0)

    f32x16 a0, a1;

    // ch0 (buf0): next-chunk DMA issued first, in flight under COMPUTE+POST
    STAGE(1, 1);
    COMPUTE(a0, 0, 0);
    COMPUTE(a1, 0, 1);
    POST(a0, 0);
    POST(a1, 1);
    __syncthreads();
    // ch1 (buf1)
    STAGE(0, 2);
    COMPUTE(a0, 1, 0);
    COMPUTE(a1, 1, 1);
    POST(a0, 2);
    POST(a1, 3);
    __syncthreads();
    // ch2 (buf0)
    STAGE(1, 3);
    COMPUTE(a0, 0, 0);
    COMPUTE(a1, 0, 1);
    POST(a0, 4);
    POST(a1, 5);
    __syncthreads();
    // ch3 (buf1)
    COMPUTE(a0, 1, 0);
    COMPUTE(a1, 1, 1);
    POST(a0, 6);
    POST(a1, 7);
    __syncthreads();

    // exp + partial denominator (no max-subtraction: |score| <= sum|w| ~ 8)
    {
        float s0 = scp[0][0][t] + scp[1][0][t];
        float s1 = scp[0][1][t] + scp[1][1][t];
        float e0 = __expf(s0), e1 = __expf(s1);
        scp[0][0][t] = e0;   // esc[0][jloc]
        scp[0][1][t] = e1;   // esc[1][jloc]
        float ss0 = e0, ss1 = e1;
        #pragma unroll
        for (int m = 1; m < 64; m <<= 1) {
            ss0 += __shfl_xor(ss0, m);
            ss1 += __shfl_xor(ss1, m);
        }
        if (lane == 0) { red_s[wid][0] = ss0; red_s[wid][1] = ss1; }
    }
    __syncthreads();
    if (t < TI) {
        float den = red_s[0][t] + red_s[1][t] + red_s[2][t] + red_s[3][t];
        pden[jh * NTOT + rid0 + t] = den;
    }

    // partial numerator over this block's 256 j  — ushort4-vectorized
    const float* esc0 = &scp[0][0][0];
    const float* esc1 = &scp[0][1][0];
    {
        const int d0 = (t & 31) * 4, q = t >> 5;   // 8 groups of 32 j
        const unsigned short* xc = xbb + (size_t)(jh * 256) * DIN + d0;
        float b0[4] = {0.f, 0.f, 0.f, 0.f};
        float b1[4] = {0.f, 0.f, 0.f, 0.f};
        #pragma unroll 4
        for (int jj = q * 32; jj < q * 32 + 32; ++jj) {
            ushort4 xv = *(const ushort4*)(xc + (size_t)jj * DIN);
            float e0v = esc0[jj], e1v = esc1[jj];
            float x0 = bf2f(xv.x), x1 = bf2f(xv.y);
            float x2 = bf2f(xv.z), x3 = bf2f(xv.w);
            b0[0] = fmaf(e0v, x0, b0[0]); b0[1] = fmaf(e0v, x1, b0[1]);
            b0[2] = fmaf(e0v, x2, b0[2]); b0[3] = fmaf(e0v, x3, b0[3]);
            b1[0] = fmaf(e1v, x0, b1[0]); b1[1] = fmaf(e1v, x1, b1[1]);
            b1[2] = fmaf(e1v, x2, b1[2]); b1[3] = fmaf(e1v, x3, b1[3]);
        }
        #pragma unroll
        for (int c = 0; c < 4; ++c) {
            pagg[(q * TI + 0) * DIN + d0 + c] = b0[c];
            pagg[(q * TI + 1) * DIN + d0 + c] = b1[c];
        }
    }
    __syncthreads();
    {
        const int i = t >> 7, d = t & 127;
        float s = 0.f;
        #pragma unroll
        for (int q = 0; q < 8; ++q) s += pagg[(q * TI + i) * DIN + d];
        pnum[(size_t)(jh * NTOT + rid0 + i) * DIN + d] = s;
    }
#undef COMPUTE
#undef POST
#undef STAGE
}

// Combine j-half partials, normalize, apply both projections, emit BN partials.
// == r20 verified version: 128 blocks x 16 rows ==
__global__ __launch_bounds__(256, 2) void combine_proj(
    const float* __restrict__ x,
    const float* __restrict__ pnum, const float* __restrict__ pden,
    const float* __restrict__ pww, const float* __restrict__ pwb,
    const float* __restrict__ pow_, const float* __restrict__ pob,
    float* __restrict__ out, float* __restrict__ pbn)   // [128][2][64]
{
    __shared__ float wL[DOUT][DIN + 1];   // 33 KB (one matrix at a time)
    __shared__ float vL[16][DIN];         // 8 KB (num, then xi)
    __shared__ float invL[16];
    __shared__ float psum[4][DOUT];
    __shared__ float psum2[4][DOUT];

    const int t = threadIdx.x;
    const int rbase = blockIdx.x * 16;
    const int o = t & 63, rq = t >> 6;    // per-wave uniform rq

    // stage W1 + unnormalized num + inv-denominators (all coalesced)
    for (int k = t; k < DOUT * DIN; k += 256) wL[k >> 7][k & 127] = pww[k];
    for (int k = t; k < 16 * DIN; k += 256) {
        const int i = k >> 7, d = k & 127;
        const int r = rbase + i;
        vL[i][d] = pnum[(size_t)r * DIN + d] + pnum[(size_t)(NTOT + r) * DIN + d];
    }
    if (t < 16) {
        const int r = rbase + t;
        invL[t] = 1.0f / (pden[r] + pden[NTOT + r]);
    }
    __syncthreads();

    // phase 1: accp[rr] = W1[o,:] . num[row rq+rr*4]
    float accp[4] = {0.f, 0.f, 0.f, 0.f};
    #pragma unroll 4
    for (int d = 0; d < DIN; ++d) {
        float w = wL[o][d];
        #pragma unroll
        for (int rr = 0; rr < 4; ++rr)
            accp[rr] = fmaf(w, vL[rq + rr * 4][d], accp[rr]);
    }
    __syncthreads();

    // restage: W2 + xi rows
    for (int k = t; k < DOUT * DIN; k += 256) wL[k >> 7][k & 127] = pow_[k];
    for (int k = t; k < 16 * DIN; k += 256) {
        const int i = k >> 7, d = k & 127;
        vL[i][d] = x[(size_t)(rbase + i) * DIN + d];
    }
    __syncthreads();

    // phase 2: res[rr] = W2[o,:] . xi[row]; combine; write; BN partials
    float res[4] = {0.f, 0.f, 0.f, 0.f};
    #pragma unroll 4
    for (int d = 0; d < DIN; ++d) {
        float w = wL[o][d];
        #pragma unroll
        for (int rr = 0; rr < 4; ++rr)
            res[rr] = fmaf(w, vL[rq + rr * 4][d], res[rr]);
    }
    const float bias = pwb[o] + pob[o];
    float ls = 0.f, ls2 = 0.f;
    #pragma unroll
    for (int rr = 0; rr < 4; ++rr) {
        const int i = rq + rr * 4;
        float h = accp[rr] * invL[i] + res[rr] + bias;
        out[(size_t)(rbase + i) * DOUT + o] = h;
        ls += h; ls2 += h * h;
    }
    psum[rq][o] = ls;
    psum2[rq][o] = ls2;
    __syncthreads();
    if (t < DOUT) {
        pbn[((size_t)blockIdx.x * 2 + 0) * DOUT + t] =
            psum[0][t] + psum[1][t] + psum[2][t] + psum[3][t];
        pbn[((size_t)blockIdx.x * 2 + 1) * DOUT + t] =
            psum2[0][t] + psum2[1][t] + psum2[2][t] + psum2[3][t];
    }
}

// BN + SELU; every block first reduces the 128 per-block partials to stats
// (redundant but deterministic; avoids a separate finish launch).
__global__ __launch_bounds__(256) void bn_selu(
    float* __restrict__ out, const float* __restrict__ pbn,
    const float* __restrict__ gamma, const float* __restrict__ beta) {
    __shared__ float ps[4][DOUT], ps2[4][DOUT];
    __shared__ float stats[2][DOUT];
    const int t = threadIdx.x;
    {
        const int c = t & 63, grp = t >> 6;   // 4 groups of 32 partial-blocks
        float s = 0.f, s2 = 0.f;
        for (int bb = grp * 32; bb < grp * 32 + 32; ++bb) {
            s += pbn[((size_t)bb * 2 + 0) * DOUT + c];
            s2 += pbn[((size_t)bb * 2 + 1) * DOUT + c];
        }
        ps[grp][c] = s;
        ps2[grp][c] = s2;
    }
    __syncthreads();
    if (t < DOUT) {
        const float inv_n = 1.0f / (float)NTOT;
        float ss = ps[0][t] + ps[1][t] + ps[2][t] + ps[3][t];
        float ss2 = ps2[0][t] + ps2[1][t] + ps2[2][t] + ps2[3][t];
        float mean = ss * inv_n;
        float var = ss2 * inv_n - mean * mean;   // biased, as torch BN
        stats[0][t] = mean;
        stats[1][t] = rsqrtf(var + 1e-5f);
    }
    __syncthreads();
    const int idx = blockIdx.x * 256 + t;
    const int c = idx & 63;
    float v = out[idx];
    float y = (v - stats[0][c]) * stats[1][c] * gamma[c] + beta[c];
    const float scale = 1.0507009873554805f;
    const float alpha = 1.6732632423543772f;
    out[idx] = y > 0.0f ? scale * y : scale * alpha * (__expf(y) - 1.0f);
}

extern "C" void kernel_launch(void* const* d_in, const int* in_sizes, int n_in,
                              void* d_out, int out_size, void* d_ws, size_t ws_size,
                              hipStream_t stream) {
    const float* x    = (const float*)d_in[0];
    const float* apw  = (const float*)d_in[1];
    const float* apb  = (const float*)d_in[2];
    const float* attw = (const float*)d_in[3];
    const float* pww  = (const float*)d_in[4];
    const float* pwb  = (const float*)d_in[5];
    const float* pow_ = (const float*)d_in[6];
    const float* pob  = (const float*)d_in[7];
    const float* gmm  = (const float*)d_in[8];
    const float* bta  = (const float*)d_in[9];
    float* out = (float*)d_out;

    char* ws = (char*)d_ws;
    unsigned short* xbf = (unsigned short*)(ws + 1024);      // 512 KB
    float* pnum = (float*)(ws + 528384);                     // 2 MB  [2][2048][128]
    float* pden = (float*)(ws + 528384 + 2097152);           // 16 KB [2][2048]
    float* pbn  = (float*)(ws + 528384 + 2097152 + 16384);   // 64 KB [128][2][64]
    unsigned short* apwf = (unsigned short*)(ws + 528384 + 2097152 + 16384 + 65536); // 16 KB

    x_to_bf16<<<257, 256, 0, stream>>>(x, xbf, apw, apwf);
    gat_main<<<2 * NTOT / TI, 256, 0, stream>>>(x, xbf, apwf, apb, attw, pnum, pden);
    combine_proj<<<NTOT / 16, 256, 0, stream>>>(x, pnum, pden, pww, pwb, pow_, pob,
                                                out, pbn);
    bn_selu<<<(NTOT * DOUT) / 256, 256, 0, stream>>>(out, pbn, gmm, bta);
}